// Round 14
// baseline (31.438 us; speedup 1.0000x reference)
//
#include <hip/hip_runtime.h>
#include <math.h>

constexpr int NB    = 128;
constexpr int NPAIR = NB * (NB - 1) / 2;        // 8128
constexpr int NANG  = NB - 2;                   // 126
constexpr int NDIH  = NB - 3;                   // 125
constexpr int ROW   = NPAIR + NANG + 2 * NDIH;  // 8504

// R13 structure, ONE variable changed: 2 proteins per block processed
// CONCURRENTLY (groups 0-3 -> protein 2b, groups 4-7 -> protein 2b+1).
// No extra barriers, same waves/occupancy/store pattern, same concurrent
// region count -- only block count halves (4096 -> 2048): dispatch-overhead probe.
__global__ __launch_bounds__(1024, 8) void protein_feat_kernel(
        const float* __restrict__ data, float* __restrict__ out) {
    __shared__ float4 s4[2][NB];                 // two proteins' coords
    const int t   = threadIdx.x;                 // 0..1023
    const int tb  = t & 127;                     // bead index
    const int gg  = t >> 7;                      // 0..7
    const int ps  = gg >> 2;                     // protein select 0/1
    const int g   = gg & 3;                      // off-group 0..3 within protein
    const int b   = blockIdx.x * 2 + ps;         // protein id

    // Stage both proteins (threads 0..255).
    if (t < 2 * NB) {
        const int pp = t >> 7, bead = t & 127;
        const float* s = data + (size_t)(blockIdx.x * 2 + pp) * (NB * 3) + 3 * bead;
        s4[pp][bead] = make_float4(s[0], s[1], s[2], 0.0f);
    }
    __syncthreads();

    float* orow = out + (size_t)b * ROW;

    // Register band: lane holds beads tb, tb-1, tb-2, tb-3 of its protein.
    float px[4], py[4], pz[4];
    #pragma unroll
    for (int k = 0; k < 4; ++k) {
        int idx = tb - k; if (idx < 0) idx = 0;  // clamped; masked at store
        float4 v = s4[ps][idx];
        px[k] = v.x; py[k] = v.y; pz[k] = v.z;
    }

    // ---- Distances: group g owns contiguous off-band 32g+1..32g+32
    // (off-quad base = 32g+4m+1, m=0..7); 4 rows per ds_read_b128
    // (conflict-free reads, stride-1 coalesced stores; 4 store insts per
    // iter form one contiguous ~1KB span since rows are memory-adjacent).
    #pragma unroll
    for (int m = 0; m < 8; ++m) {
        const int off = 32 * g + 4 * m + 1;
        const int len = NB - off;
        const int bk0 = (off - 1) * (2 * NB - off) / 2;  // B(off)
        const int bk1 = bk0 + len;
        const int bk2 = bk1 + len - 1;
        const int bk3 = bk2 + len - 2;
        if (tb < len) {                          // high groups execz-skip tails
            float4 pj = s4[ps][tb + off];
            float dx, dy, dz, d;
            dx = pj.x - px[0]; dy = pj.y - py[0]; dz = pj.z - pz[0];
            d = __builtin_amdgcn_sqrtf(dx*dx + dy*dy + dz*dz);
            orow[bk0 + tb] = d;
            dx = pj.x - px[1]; dy = pj.y - py[1]; dz = pj.z - pz[1];
            d = __builtin_amdgcn_sqrtf(dx*dx + dy*dy + dz*dz);
            if (tb >= 1) orow[bk1 + tb - 1] = d;
            dx = pj.x - px[2]; dy = pj.y - py[2]; dz = pj.z - pz[2];
            d = __builtin_amdgcn_sqrtf(dx*dx + dy*dy + dz*dz);
            if (tb >= 2) orow[bk2 + tb - 2] = d;
            dx = pj.x - px[3]; dy = pj.y - py[3]; dz = pj.z - pz[3];
            d = __builtin_amdgcn_sqrtf(dx*dx + dy*dy + dz*dz);
            if (tb >= 3) orow[bk3 + tb - 3] = d;
        }
    }

    // ---- Angles + dihedrals: first 376 threads of each 512-thread half
    // handle their own protein (v = t&511; t<512 <=> ps==0).
    const int v = t & 511;
    if (v < NANG + 2 * NDIH) {
        if (v < NANG) {
            int a = v;
            float4 p0 = s4[ps][a], p1 = s4[ps][a + 1], p2 = s4[ps][a + 2];
            float a0x = p1.x - p0.x, a0y = p1.y - p0.y, a0z = p1.z - p0.z;
            float a1x = p2.x - p1.x, a1y = p2.y - p1.y, a1z = p2.z - p1.z;
            float d  = a0x * a1x + a0y * a1y + a0z * a1z;
            float r0 = rsqrtf(a0x * a0x + a0y * a0y + a0z * a0z);
            float r1 = rsqrtf(a1x * a1x + a1y * a1y + a1z * a1z);
            float c  = d * r0 * r1;
            c = fminf(1.0f, fmaxf(-1.0f, c));
            orow[NPAIR + a] = acosf(c);
        } else {
            int a = (v < NANG + NDIH) ? (v - NANG) : (v - NANG - NDIH);
            float4 p0 = s4[ps][a],     p1 = s4[ps][a + 1];
            float4 p2 = s4[ps][a + 2], p3 = s4[ps][a + 3];
            float e0x = p1.x - p0.x, e0y = p1.y - p0.y, e0z = p1.z - p0.z;
            float e1x = p2.x - p1.x, e1y = p2.y - p1.y, e1z = p2.z - p1.z;
            float e2x = p3.x - p2.x, e2y = p3.y - p2.y, e2z = p3.z - p2.z;
            float c0x = e0y * e1z - e0z * e1y;
            float c0y = e0z * e1x - e0x * e1z;
            float c0z = e0x * e1y - e0y * e1x;
            float c1x = e1y * e2z - e1z * e2y;
            float c1y = e1z * e2x - e1x * e2z;
            float c1z = e1x * e2y - e1y * e2x;
            float rn0 = rsqrtf(c0x * c0x + c0y * c0y + c0z * c0z);
            if (v < NANG + NDIH) {
                float d   = c0x * c1x + c0y * c1y + c0z * c1z;
                float rn1 = rsqrtf(c1x * c1x + c1y * c1y + c1z * c1z);
                orow[NPAIR + NANG + a] = d * rn0 * rn1;
            } else {
                float qx = c1y * e1z - c1z * e1y;   // plane = c1 x e1
                float qy = c1z * e1x - c1x * e1z;
                float qz = c1x * e1y - c1y * e1x;
                float d  = c0x * qx + c0y * qy + c0z * qz;
                float rp = rsqrtf(qx * qx + qy * qy + qz * qz);
                orow[NPAIR + NANG + NDIH + a] = d * rn0 * rp;
            }
        }
    }
}

extern "C" void kernel_launch(void* const* d_in, const int* in_sizes, int n_in,
                              void* d_out, int out_size, void* d_ws, size_t ws_size,
                              hipStream_t stream) {
    const float* data = (const float*)d_in[0];
    float* out = (float*)d_out;
    const int batch = in_sizes[0] / (NB * 3);   // 4096
    protein_feat_kernel<<<batch / 2, 1024, 0, stream>>>(data, out);
}